// Round 5
// baseline (1114.261 us; speedup 1.0000x reference)
//
#include <hip/hip_runtime.h>

#define N_    64
#define C_    64
#define T_    300
#define V_    25
#define IC_   16
#define TV_   7500      // T*V
#define CTV_  480000    // C*T*V  (per-n x slice)

typedef __attribute__((ext_vector_type(8))) short short8;
typedef __attribute__((ext_vector_type(4))) short sh4;
typedef __attribute__((ext_vector_type(4))) float f32x4;

static __device__ inline short f2bf(float f) {
    unsigned u = __float_as_uint(f);
    unsigned r = (u + 0x7fff + ((u >> 16) & 1)) >> 16;
    return (short)r;
}
static __device__ inline float bf2f(short s) {
    return __uint_as_float(((unsigned)(unsigned short)s) << 16);
}

// ---------------- prep_all: wprep (bx<650) + dwprep (650..697) + amix (698) ----------------
__global__ void prep_all(
    const float* __restrict__ a_w, const float* __restrict__ b_w,
    const float* __restrict__ t1_w, const float* __restrict__ t2_w,
    const float* __restrict__ st11_w1, const float* __restrict__ st12_w1,
    const float* __restrict__ st11_w9, const float* __restrict__ st12_w9,
    const float* __restrict__ a_b, const float* __restrict__ b_b,
    const float* __restrict__ t1_b, const float* __restrict__ t2_b,
    const float* __restrict__ st11_b, const float* __restrict__ st12_b,
    const float* __restrict__ dw, const float* __restrict__ db,
    const float* __restrict__ A, const float* __restrict__ wts,
    short* __restrict__ wpk_all, float* __restrict__ bpk,
    short* __restrict__ dwpk, float* __restrict__ db_sum,
    float* __restrict__ amix) {
    int bx = blockIdx.x;
    int tid = threadIdx.x;

    if (bx < 650) {  // ---- wprep_all ----
        int idx = bx * 256 + tid;
        int pair, r;
        bool bias_path = false;
        if (idx < 9 * 18432) {
            pair = idx / 18432; r = idx - pair * 18432;
        } else if (idx < 9 * 18432 + 288) {
            bias_path = true;
            int bidx = idx - 9 * 18432;
            pair = bidx >> 5; r = bidx & 31;
        } else return;

        const float *w1, *w2, *bb1, *bb2; int taps;
        switch (pair) {
            case 0: taps=1; w1=a_w;          w2=b_w;          bb1=a_b;       bb2=b_b;       break;
            case 1: taps=9; w1=t1_w;         w2=t2_w;         bb1=t1_b;      bb2=t2_b;      break;
            case 2: taps=1; w1=st11_w1;      w2=st12_w1;      bb1=st11_b;    bb2=st12_b;    break;
            case 3: taps=1; w1=a_w+1024;     w2=b_w+1024;     bb1=a_b+16;    bb2=b_b+16;    break;
            case 4: taps=9; w1=t1_w+9216;    w2=t2_w+9216;    bb1=t1_b+16;   bb2=t2_b+16;   break;
            case 5: taps=9; w1=st11_w9;      w2=st12_w9;      bb1=st11_b+16; bb2=st12_b+16; break;
            case 6: taps=1; w1=a_w+2048;     w2=b_w+2048;     bb1=a_b+32;    bb2=b_b+32;    break;
            case 7: taps=9; w1=t1_w+18432;   w2=t2_w+18432;   bb1=t1_b+32;   bb2=t2_b+32;   break;
            default: taps=1; w1=st11_w1+1024; w2=st12_w1+1024; bb1=st11_b+32; bb2=st12_b+32; break;
        }
        if (bias_path) {
            int half = r >> 4, o = r & 15;
            bpk[pair * 32 + r] = half ? bb2[o] : bb1[o];
            return;
        }
        if (r >= taps * 2048) return;
        int j = r & 7;
        int l = (r >> 3) & 63;
        int half = (r >> 9) & 1;
        int kk = r >> 10;
        int K = kk * 32 + ((l >> 4) << 3) + j;
        int c = K & 63, k = K >> 6;
        int o = l & 15;
        const float* w = half ? w2 : w1;
        wpk_all[pair * 18432 + r] = f2bf(w[(o * 64 + c) * taps + k]);
        return;
    }
    if (bx < 698) {  // ---- dwprep ----
        int idx = (bx - 650) * 256 + tid;
        if (idx < 12288) {
            int j = idx & 7;
            int lane = (idx >> 3) & 63;
            int kk = (idx >> 9) & 1;
            int mt = idx >> 10;
            int R = mt * 16 + (lane & 15);
            int c = kk * 32 + ((lane >> 4) << 3) + j;
            int i = R >> 6, o = R & 63;
            dwpk[idx] = f2bf(dw[i * 4096 + o * 64 + c]);
        }
        if (idx < 64) db_sum[idx] = db[idx] + db[64 + idx] + db[128 + idx];
        return;
    }
    // ---- amix ----
    if (tid >= 75) return;
    int s = tid / 25, col = tid % 25;
    const float* As = A + s * 625;
    float av[25], ch4[25];
#pragma unroll
    for (int r = 0; r < 25; ++r) {
        float a = As[r * 25 + col];
        float a2 = a * a;
        float eye = (r == col) ? 1.f : 0.f;
        av[r] = a;
        ch4[r] = 8.f * a2 * a2 - 8.f * a2 + eye;
    }
    float m = -1e30f;
#pragma unroll
    for (int r = 0; r < 25; ++r) m = fmaxf(m, ch4[r] * (1.f / 25.f));
    float e[25];
    float sum = 0.f;
#pragma unroll
    for (int r = 0; r < 25; ++r) { e[r] = __expf(ch4[r] * (1.f / 25.f) - m); sum += e[r]; }
    float inv = 1.f / sum;
    float w0 = wts[0], w1 = wts[1], w2 = wts[2], w3 = wts[3], w4 = wts[4];
#pragma unroll
    for (int r = 0; r < 25; ++r) {
        float a = av[r], a2 = a * a;
        float eye = (r == col) ? 1.f : 0.f;
        amix[s * 625 + r * 25 + col] =
            w0 * a + w1 * (e[r] * inv) + w2 * ch4[r] +
            w3 * (4.f * a2 * a - 3.f * a) + w4 * (2.f * a2 - eye);
    }
}

// ---------------- conv helpers ----------------
template <int CNT>
static __device__ __attribute__((always_inline)) void conv_onetap(
    const int (&PL)[CNT], const short* __restrict__ wpk_all, const short* xs,
    int pw, int lane, f32x4 (*acc)[2][2]) {
    int q = lane >> 4, m = lane & 15;
#pragma unroll
    for (int kc2 = 0; kc2 < 2; ++kc2) {
        int c0 = kc2 * 32;
        short8 b0 = *(const short8*)(xs + (pw + m + 100) * 72 + c0 + q * 8);
        short8 b1 = *(const short8*)(xs + (pw + m + 116) * 72 + c0 + q * 8);
#pragma unroll
        for (int pi = 0; pi < CNT; ++pi) {
            const short* wp = wpk_all + PL[pi] * 18432 + kc2 * 1024 + lane * 8;
            short8 a0 = *(const short8*)(wp);
            short8 a1 = *(const short8*)(wp + 512);
            acc[pi][0][0] = __builtin_amdgcn_mfma_f32_16x16x32_bf16(a0, b0, acc[pi][0][0], 0, 0, 0);
            acc[pi][0][1] = __builtin_amdgcn_mfma_f32_16x16x32_bf16(a0, b1, acc[pi][0][1], 0, 0, 0);
            acc[pi][1][0] = __builtin_amdgcn_mfma_f32_16x16x32_bf16(a1, b0, acc[pi][1][0], 0, 0, 0);
            acc[pi][1][1] = __builtin_amdgcn_mfma_f32_16x16x32_bf16(a1, b1, acc[pi][1][1], 0, 0, 0);
        }
    }
}

template <int CNT>
static __device__ __attribute__((always_inline)) void conv_ninetap(
    const int (&PL)[CNT], const short* __restrict__ wpk_all, const short* xs,
    int pw, int lane, f32x4 (*acc)[2][2]) {
    int q = lane >> 4, m = lane & 15;
#pragma unroll
    for (int kc = 0; kc < 18; ++kc) {
        int k = kc >> 1;
        int c0 = (kc & 1) * 32;
        short8 b0 = *(const short8*)(xs + (pw + m + 25 * k) * 72 + c0 + q * 8);
        short8 b1 = *(const short8*)(xs + (pw + m + 25 * k + 16) * 72 + c0 + q * 8);
#pragma unroll
        for (int pi = 0; pi < CNT; ++pi) {
            const short* wp = wpk_all + PL[pi] * 18432 + kc * 1024 + lane * 8;
            short8 a0 = *(const short8*)(wp);
            short8 a1 = *(const short8*)(wp + 512);
            acc[pi][0][0] = __builtin_amdgcn_mfma_f32_16x16x32_bf16(a0, b0, acc[pi][0][0], 0, 0, 0);
            acc[pi][0][1] = __builtin_amdgcn_mfma_f32_16x16x32_bf16(a0, b1, acc[pi][0][1], 0, 0, 0);
            acc[pi][1][0] = __builtin_amdgcn_mfma_f32_16x16x32_bf16(a1, b0, acc[pi][1][0], 0, 0, 0);
            acc[pi][1][1] = __builtin_amdgcn_mfma_f32_16x16x32_bf16(a1, b1, acc[pi][1][1], 0, 0, 0);
        }
    }
}

// ---------------- epilogue pieces ----------------
static __device__ __attribute__((always_inline)) void fT_write(
    const f32x4 acc[2][2], int pair, short* fb, const float* __restrict__ bpk,
    int wq, int lane) {
    int q = lane >> 4, m = lane & 15;
    int pw = wq * 32;
    f32x4 bh0 = *(const f32x4*)(bpk + pair * 32 + q * 4);
    f32x4 bh1 = *(const f32x4*)(bpk + pair * 32 + 16 + q * 4);
#pragma unroll
    for (int h = 0; h < 2; ++h) {
#pragma unroll
        for (int nt = 0; nt < 2; ++nt) {
            int p = pw + nt * 16 + m;
            if (p < 125) {
                int tl = p / 25, v = p - tl * 25;
                sh4 pk;
#pragma unroll
                for (int r = 0; r < 4; ++r) {
                    float bv = h ? bh1[r] : bh0[r];
                    pk[r] = f2bf(acc[h][nt][r] + bv);
                }
                *(sh4*)(fb + h * 3328 + v * 104 + tl * 16 + q * 4) = pk;
            }
        }
    }
}

static __device__ __attribute__((always_inline)) void gram_store(
    const short* fb, int pair, short* __restrict__ Gpart, int n, int ch,
    int wq, int lane) {
    int q = lane >> 4, m = lane & 15;
    int mt = wq >> 1, ntl = wq & 1;
    f32x4 g = (f32x4)(0.f);
#pragma unroll
    for (int s = 0; s < 3; ++s) {
        short8 af = *(const short8*)(fb + (mt * 16 + m) * 104 + s * 32 + q * 8);
        short8 bf = *(const short8*)(fb + 3328 + (ntl * 16 + m) * 104 + s * 32 + q * 8);
        g = __builtin_amdgcn_mfma_f32_16x16x32_bf16(af, bf, g, 0, 0, 0);
    }
    int gvp = ntl * 16 + m;
    if (gvp < 25) {
        short* gdst = Gpart + ((pair * 64 + n) * 60 + ch) * 625 + gvp;
#pragma unroll
        for (int r = 0; r < 4; ++r) {
            int v = mt * 16 + q * 4 + r;
            if (v < 25) gdst[v * 25] = f2bf(g[r]);
        }
    }
}

// ---------------- fused conv + gram (8 waves, 2 wave-groups) ----------------
__global__ __launch_bounds__(512, 4) void convgram(
    const float* __restrict__ x, const short* __restrict__ wpk_all,
    const float* __restrict__ bpk, short* __restrict__ Gpart) {
    __shared__ __align__(16) short xs[328 * 72];      // 47,232 B
    __shared__ __align__(16) short fTb[2 * 6656];     // 26,624 B (one buf per group)
    int tid = threadIdx.x;
    int n = blockIdx.y, ch = blockIdx.x;
    int p0 = ch * 125;
    const float* xn = x + n * CTV_;

    for (int g = 0; g < 5; ++g) {
        float vb[8]; int ib[8];
#pragma unroll
        for (int u = 0; u < 8; ++u) {
            int jj = tid + (g * 8 + u) * 512;
            int c = jj / 328, rr = jj - c * 328;
            int pp = p0 - 100 + rr;
            vb[u] = (pp >= 0 && pp < TV_) ? xn[c * TV_ + pp] : 0.f;
            ib[u] = rr * 72 + c;
        }
#pragma unroll
        for (int u = 0; u < 8; ++u) xs[ib[u]] = f2bf(vb[u]);
    }
    {
        int jj = tid + 40 * 512;
        int c = jj / 328, rr = jj - c * 328;
        int pp = p0 - 100 + rr;
        xs[rr * 72 + c] = f2bf((pp >= 0 && pp < TV_) ? xn[c * TV_ + pp] : 0.f);
    }
    for (int jj = tid; jj < 6656; jj += 512) ((int*)fTb)[jj] = 0;
    __syncthreads();

    int wave = tid >> 6, lane = tid & 63;
    int wq = wave & 3, grp = wave >> 2;
    int pw = wq * 32;
    short* fb = fTb + grp * 6656;

    {   // one-tap pairs
        f32x4 acc3[3][2][2];
#pragma unroll
        for (int p = 0; p < 3; ++p)
#pragma unroll
            for (int h = 0; h < 2; ++h)
#pragma unroll
                for (int nt = 0; nt < 2; ++nt) acc3[p][h][nt] = (f32x4)(0.f);
        if (grp == 0) {
            const int PL[3] = {0, 2, 3};
            conv_onetap<3>(PL, wpk_all, xs, pw, lane, acc3);
        } else {
            const int PL[2] = {6, 8};
            conv_onetap<2>(PL, wpk_all, xs, pw, lane, acc3);
        }
        const int pl0[3] = {0, 2, 3}, pl1[3] = {6, 8, 0};
        int npair = (grp == 0) ? 3 : 2;
#pragma unroll
        for (int r = 0; r < 3; ++r) {
            bool valid = r < npair;
            int pair = (grp == 0) ? pl0[r] : pl1[r];
            if (valid) fT_write(acc3[r], pair, fb, bpk, wq, lane);
            __syncthreads();
            if (valid) gram_store(fb, pair, Gpart, n, ch, wq, lane);
            __syncthreads();
        }
    }

    {   // nine-tap pairs
        f32x4 acc2[2][2][2];
#pragma unroll
        for (int p = 0; p < 2; ++p)
#pragma unroll
            for (int h = 0; h < 2; ++h)
#pragma unroll
                for (int nt = 0; nt < 2; ++nt) acc2[p][h][nt] = (f32x4)(0.f);
        if (grp == 0) {
            const int PL[2] = {1, 4};
            conv_ninetap<2>(PL, wpk_all, xs, pw, lane, acc2);
        } else {
            const int PL[2] = {5, 7};
            conv_ninetap<2>(PL, wpk_all, xs, pw, lane, acc2);
        }
        const int plA[2] = {1, 4}, plB[2] = {5, 7};
#pragma unroll
        for (int r = 0; r < 2; ++r) {
            int pair = (grp == 0) ? plA[r] : plB[r];
            fT_write(acc2[r], pair, fb, bpk, wq, lane);
            __syncthreads();
            gram_store(fb, pair, Gpart, n, ch, wq, lane);
            __syncthreads();
        }
    }
}

// ---------------- finalize + aprep merged: grid (64 n, 3 i) ----------------
__global__ __launch_bounds__(256) void finalize_aprep(
    const short* __restrict__ Gpart, const float* __restrict__ amix,
    const float* __restrict__ wts, short* __restrict__ apk) {
    __shared__ float sm[3 * 625];
    int n = blockIdx.x, i = blockIdx.y;
    int tid = threadIdx.x;
#pragma unroll
    for (int pi = 0; pi < 3; ++pi) {
        int pair = i * 3 + pi;
        const short* g = Gpart + (pair * 64 + n) * 60 * 625;
        for (int qq = tid; qq < 625; qq += 256) {
            float s = 0.f;
#pragma unroll
            for (int ch = 0; ch < 60; ++ch) s += bf2f(g[ch * 625 + qq]);
            sm[pi * 625 + qq] = s * (1.f / 4800.f);
        }
    }
    __syncthreads();
    if (tid < 75) {
        int pi = tid / 25, col = tid % 25;
        float* smp = sm + pi * 625;
        float m = -1e30f;
#pragma unroll
        for (int r = 0; r < 25; ++r) m = fmaxf(m, smp[r * 25 + col]);
        float e[25];
        float sum = 0.f;
#pragma unroll
        for (int r = 0; r < 25; ++r) { e[r] = __expf(smp[r * 25 + col] - m); sum += e[r]; }
        float inv = 1.f / sum;
#pragma unroll
        for (int r = 0; r < 25; ++r) smp[r * 25 + col] = e[r] * inv;
    }
    __syncthreads();
    float w5 = wts[5], w6 = wts[6], w7 = wts[7];
#pragma unroll
    for (int it = 0; it < 5; ++it) {
        int rem = tid + it * 256;
        int v = rem / 40, vp = rem - v * 40;
        float val = 0.f;
        if (v < 25 && vp < 25) {
            int e = vp * 25 + v;
            val = amix[i * 625 + e] + w5 * sm[e] + w6 * sm[625 + e] + w7 * sm[1250 + e];
        }
        apk[n * 3840 + i * 1280 + rem] = f2bf(val);
    }
}

// ---------------- xbf_prep: x[n][c][p] f32 -> xbf[n][p][c] bf16 ----------------
__global__ __launch_bounds__(256) void xbf_prep(
    const float* __restrict__ x, short* __restrict__ xbf) {
    __shared__ __align__(16) float tile[64 * 128];   // [c][pp] 32 KiB
    int n = blockIdx.y;
    int p0 = blockIdx.x * 128;
    int tid = threadIdx.x;
    const float* xn = x + n * CTV_;
#pragma unroll
    for (int it = 0; it < 8; ++it) {
        int unit = tid + it * 256;          // 2048 float4 units
        int c = unit >> 5, pf = unit & 31;
        int p = p0 + pf * 4;
        f32x4 v;
        if (p + 3 < TV_) {
            v = *(const f32x4*)(xn + c * TV_ + p);
        } else {
#pragma unroll
            for (int j = 0; j < 4; ++j) v[j] = (p + j < TV_) ? xn[c * TV_ + p + j] : 0.f;
        }
        *(f32x4*)(tile + c * 128 + pf * 4) = v;
    }
    __syncthreads();
#pragma unroll
    for (int it = 0; it < 4; ++it) {
        int unit = tid + it * 256;          // 1024 short8 units
        int pp = unit >> 3, cb = unit & 7;
        if (p0 + pp < TV_) {
            short8 o;
#pragma unroll
            for (int k = 0; k < 8; ++k) o[k] = f2bf(tile[(cb * 8 + k) * 128 + pp]);
            *(short8*)(xbf + ((size_t)n * TV_ + p0 + pp) * 64 + cb * 8) = o;
        }
    }
}

// ---------------- mega: xbf-direct b-frags, us-only LDS, atomic BN stats ----------------
__global__ __launch_bounds__(256, 4) void mega(
    const short* __restrict__ xbf, const short* __restrict__ apk,
    const short* __restrict__ dwpk, const float* __restrict__ db_sum,
    float* __restrict__ out, float* __restrict__ stats) {
    __shared__ __align__(16) short us[3 * 64 * 104];  // 39,936 B

    int tid = threadIdx.x;
    int n = blockIdx.y;
    int t0 = blockIdx.x * 3;
    const short* xb = xbf + (size_t)n * TV_ * 64 + t0 * 25 * 64;

    int wave = tid >> 6, lane = tid & 63;
    int q = lane >> 4, m = lane & 15;

    short8 af[3][2];
#pragma unroll
    for (int mt = 0; mt < 3; ++mt)
#pragma unroll
        for (int kk = 0; kk < 2; ++kk)
            af[mt][kk] = *(const short8*)(dwpk + ((wave * 3 + mt) * 2 + kk) * 512 + lane * 8);
    const short* an = apk + n * 3840;
    short8 bfr[3][2];
#pragma unroll
    for (int i = 0; i < 3; ++i)
#pragma unroll
        for (int nt = 0; nt < 2; ++nt)
            bfr[i][nt] = *(const short8*)(an + (i * 32 + nt * 16 + m) * 40 + q * 8);
    float db4[4];
#pragma unroll
    for (int r = 0; r < 4; ++r) db4[r] = db_sum[wave * 16 + q * 4 + r];

    // zero us pads (vectorized)
    for (int jj = tid; jj < 2496; jj += 256) *(short8*)(us + jj * 8) = (short8)(short)0;

    f32x4 acc[3][5];
#pragma unroll
    for (int mt = 0; mt < 3; ++mt)
#pragma unroll
        for (int nt = 0; nt < 5; ++nt) acc[mt][nt] = (f32x4)(0.f);

#pragma unroll
    for (int nt = 0; nt < 5; ++nt) {
        int pl = nt * 16 + m;
        bool ok = pl < 75;
        const short* bp = xb + pl * 64 + q * 8;
        short8 b0 = ok ? *(const short8*)(bp) : (short8)(short)0;
        short8 b1 = ok ? *(const short8*)(bp + 32) : (short8)(short)0;
#pragma unroll
        for (int mt = 0; mt < 3; ++mt) {
            acc[mt][nt] = __builtin_amdgcn_mfma_f32_16x16x32_bf16(af[mt][0], b0, acc[mt][nt], 0, 0, 0);
            acc[mt][nt] = __builtin_amdgcn_mfma_f32_16x16x32_bf16(af[mt][1], b1, acc[mt][nt], 0, 0, 0);
        }
    }
    __syncthreads();   // us zero complete before data writes land
#pragma unroll
    for (int nt = 0; nt < 5; ++nt) {
        int p = nt * 16 + m;
        if (p < 75) {
            int t = p / 25, vp = p - t * 25;
            int base = t * 6656 + vp;
#pragma unroll
            for (int mt = 0; mt < 3; ++mt) {
#pragma unroll
                for (int r = 0; r < 4; ++r) {
                    int R = wave * 48 + mt * 16 + q * 4 + r;
                    int i = R >> 6, o = R & 63;
                    us[base + o * 104 + i * 32] = f2bf(acc[mt][nt][r]);
                }
            }
        }
    }
    __syncthreads();

    float sr[4] = {0.f, 0.f, 0.f, 0.f}, s2r[4] = {0.f, 0.f, 0.f, 0.f};
    float* yb = out + n * CTV_ + t0 * 25;
#pragma unroll
    for (int t = 0; t < 3; ++t) {
        f32x4 a2[2];
        a2[0] = (f32x4)(0.f);
        a2[1] = (f32x4)(0.f);
#pragma unroll
        for (int i = 0; i < 3; ++i) {
            short8 ua = *(const short8*)(us + t * 6656 + (wave * 16 + m) * 104 + i * 32 + q * 8);
            a2[0] = __builtin_amdgcn_mfma_f32_16x16x32_bf16(ua, bfr[i][0], a2[0], 0, 0, 0);
            a2[1] = __builtin_amdgcn_mfma_f32_16x16x32_bf16(ua, bfr[i][1], a2[1], 0, 0, 0);
        }
#pragma unroll
        for (int nt = 0; nt < 2; ++nt) {
            int v = nt * 16 + m;
            if (v < 25) {
#pragma unroll
                for (int r = 0; r < 4; ++r) {
                    int o = wave * 16 + q * 4 + r;
                    float val = a2[nt][r] + db4[r];
                    yb[o * TV_ + t * 25 + v] = val;
                    sr[r] += val;
                    s2r[r] += val * val;
                }
            }
        }
    }

#pragma unroll
    for (int r = 0; r < 4; ++r) {
        float s = sr[r], s2 = s2r[r];
#pragma unroll
        for (int d = 1; d < 16; d <<= 1) {
            s += __shfl_xor(s, d, 64);
            s2 += __shfl_xor(s2, d, 64);
        }
        if (m == 0) {
            int o = wave * 16 + q * 4 + r;
            atomicAdd(&stats[o], s);
            atomicAdd(&stats[64 + o], s2);
        }
    }
}

// ---------------- BN apply + residual + relu, float4 ----------------
__global__ __launch_bounds__(256) void bn_final4(
    const float* __restrict__ x, const float* __restrict__ stats,
    const float* __restrict__ bnw, const float* __restrict__ bnb,
    float* __restrict__ y) {
    int idx = blockIdx.x * 256 + threadIdx.x;   // 7,680,000 float4s
    int o = (idx / 1875) & 63;                  // TV_/4 = 1875
    const float cnt = (float)(N_ * TV_);
    float mu = stats[o] / cnt;
    float var = stats[64 + o] / cnt - mu * mu;
    float inv = rsqrtf(var + 1e-5f);
    float w = bnw[o], b = bnb[o];
    f32x4 yv = ((const f32x4*)y)[idx];
    f32x4 xv = ((const f32x4*)x)[idx];
    f32x4 r;
#pragma unroll
    for (int k = 0; k < 4; ++k) r[k] = fmaxf((yv[k] - mu) * inv * w + b + xv[k], 0.f);
    ((f32x4*)y)[idx] = r;
}

extern "C" void kernel_launch(void* const* d_in, const int* in_sizes, int n_in,
                              void* d_out, int out_size, void* d_ws, size_t ws_size,
                              hipStream_t stream) {
    (void)in_sizes; (void)n_in; (void)out_size; (void)ws_size;
    const float* x     = (const float*)d_in[0];
    const float* wts   = (const float*)d_in[1];
    const float* A     = (const float*)d_in[2];
    const float* a_w   = (const float*)d_in[3];
    const float* a_b   = (const float*)d_in[4];
    const float* b_w   = (const float*)d_in[5];
    const float* b_b   = (const float*)d_in[6];
    const float* d_wp  = (const float*)d_in[7];
    const float* d_bp  = (const float*)d_in[8];
    const float* t1_w  = (const float*)d_in[9];
    const float* t1_b  = (const float*)d_in[10];
    const float* t2_w  = (const float*)d_in[11];
    const float* t2_b  = (const float*)d_in[12];
    const float* st11_w1 = (const float*)d_in[13];
    const float* st11_w9 = (const float*)d_in[14];
    const float* st11_b  = (const float*)d_in[15];
    const float* st12_w1 = (const float*)d_in[16];
    const float* st12_w9 = (const float*)d_in[17];
    const float* st12_b  = (const float*)d_in[18];
    const float* bn_w  = (const float*)d_in[19];
    const float* bn_b  = (const float*)d_in[20];
    float* out = (float*)d_out;

    // ---- workspace layout ----
    // amix     [0        , 32,768)
    // stats    [32,768   , 33,280)      128 f32 (atomic accum)
    // db_sum   [36,864   , 37,120)
    // bpk      [40,960   , 42,112)
    // dwpk     [49,152   , 73,728)
    // wpk_all  [81,920   , 413,696)
    // apk      [425,984  , 917,504)     bf16 [64][3840]
    // Gpart    [1,048,576, 44,248,576)  bf16 [9][64][60][625]  (dead after finalize)
    // xbf      [1,048,576, 62,488,576)  bf16 [64][7500][64]    (OVERLAYS Gpart;
    //                                   written by xbf_prep strictly after finalize reads)
    // peak use 62.5 MB < 64.27 MB proven in earlier rounds.
    char* ws = (char*)d_ws;
    float* amix     = (float*)(ws);
    float* stats    = (float*)(ws + 32768);
    float* db_sum   = (float*)(ws + 36864);
    float* bpk      = (float*)(ws + 40960);
    short* dwpk     = (short*)(ws + 49152);
    short* wpk_all  = (short*)(ws + 81920);
    short* apk      = (short*)(ws + 425984);
    short* Gpart    = (short*)(ws + 1048576);
    short* xbf      = (short*)(ws + 1048576);

    prep_all<<<699, 256, 0, stream>>>(a_w, b_w, t1_w, t2_w, st11_w1, st12_w1,
                                      st11_w9, st12_w9, a_b, b_b, t1_b, t2_b,
                                      st11_b, st12_b, d_wp, d_bp, A, wts,
                                      wpk_all, bpk, dwpk, db_sum, amix);
    hipMemsetAsync(stats, 0, 512, stream);
    convgram<<<dim3(60, 64), 512, 0, stream>>>(x, wpk_all, bpk, Gpart);
    finalize_aprep<<<dim3(64, 3), 256, 0, stream>>>(Gpart, amix, wts, apk);
    xbf_prep<<<dim3(59, 64), 256, 0, stream>>>(x, xbf);
    mega<<<dim3(100, 64), 256, 0, stream>>>(xbf, apk, dwpk, db_sum, out, stats);
    bn_final4<<<30000, 256, 0, stream>>>(x, stats, bn_w, bn_b, out);
}